// Round 1
// baseline (682.829 us; speedup 1.0000x reference)
//
#include <hip/hip_runtime.h>
#include <hip/hip_bf16.h>

// ---------------- problem constants ----------------
#define T_TOK 2048
#define DMODEL 1024
#define DMLP 4096
#define NEXP 8

// MFMA fragment types (gfx950 16x16x32 bf16)
typedef __bf16 bf16x8 __attribute__((ext_vector_type(8)));
typedef float f32x4 __attribute__((ext_vector_type(4)));

__device__ __forceinline__ unsigned short f2bf(float f) {
  return __builtin_bit_cast(unsigned short, (__bf16)f);
}

// ---------------- kernel 1: router ----------------
// one wave per token: logits = h @ Wgate, fp32 softmax, top-2, renorm
__global__ __launch_bounds__(64) void router_k(
    const float* __restrict__ x, const float* __restrict__ wg,
    int* __restrict__ topi, float* __restrict__ topw) {
  int t = blockIdx.x;
  int lane = threadIdx.x;
  const float* hx = x + (size_t)t * DMODEL;
  float acc[NEXP];
#pragma unroll
  for (int e = 0; e < NEXP; ++e) acc[e] = 0.f;
  for (int i = lane; i < DMODEL; i += 64) {
    float xi = hx[i];
    const float* w = wg + (size_t)i * NEXP;
#pragma unroll
    for (int e = 0; e < NEXP; ++e) acc[e] += xi * w[e];
  }
#pragma unroll
  for (int off = 32; off > 0; off >>= 1) {
#pragma unroll
    for (int e = 0; e < NEXP; ++e) acc[e] += __shfl_down(acc[e], off);
  }
  if (lane == 0) {
    float m = acc[0];
#pragma unroll
    for (int e = 1; e < NEXP; ++e) m = fmaxf(m, acc[e]);
    float p[NEXP], s = 0.f;
#pragma unroll
    for (int e = 0; e < NEXP; ++e) { p[e] = expf(acc[e] - m); s += p[e]; }
    float inv = 1.f / s;
#pragma unroll
    for (int e = 0; e < NEXP; ++e) p[e] *= inv;
    // top-2, ties -> lower index first (matches jax.lax.top_k)
    int i1 = 0;
#pragma unroll
    for (int e = 1; e < NEXP; ++e) if (p[e] > p[i1]) i1 = e;
    int i2 = (i1 == 0) ? 1 : 0;
#pragma unroll
    for (int e = 0; e < NEXP; ++e) if (e != i1 && p[e] > p[i2]) i2 = e;
    float w1 = p[i1], w2 = p[i2];
    float rs = 1.f / (w1 + w2);
    topi[2 * t] = i1;
    topi[2 * t + 1] = i2;
    topw[2 * t] = w1 * rs;
    topw[2 * t + 1] = w2 * rs;
  }
}

// ---------------- kernel 2: per-expert compaction ----------------
// 8 waves, wave e compacts token list of expert e via ballot prefix sums.
__global__ __launch_bounds__(512) void compact_k(
    const int* __restrict__ topi, const float* __restrict__ topw,
    int* __restrict__ offsets, int* __restrict__ perm,
    float* __restrict__ wrow) {
  int tid = threadIdx.x;
  int e = tid >> 6, lane = tid & 63;
  __shared__ int scnt[NEXP];
  __shared__ int soff[NEXP + 1];
  int c = 0;
  for (int j = lane; j < 2 * T_TOK; j += 64) {
    unsigned long long m = __ballot(topi[j] == e);
    c += __popcll(m);
  }
  if (lane == 0) scnt[e] = c;
  __syncthreads();
  if (tid == 0) {
    int s = 0;
    for (int k = 0; k < NEXP; ++k) { soff[k] = s; s += scnt[k]; }
    soff[NEXP] = s;
    for (int k = 0; k <= NEXP; ++k) offsets[k] = soff[k];
  }
  __syncthreads();
  int base = soff[e];
  for (int j = lane; j < 2 * T_TOK; j += 64) {
    bool f = (topi[j] == e);
    unsigned long long m = __ballot(f);
    if (f) {
      int p = base + __popcll(m & ((1ULL << lane) - 1ULL));
      perm[p] = j >> 1;          // token id
      wrow[p] = topw[j];         // combine weight
    }
    base += __popcll(m);
  }
}

// ---------------- kernel 3: fused gate/in GEMM + silu ----------------
// Per expert e: hid[pos, :] = wrow[pos] * silu(H@Wg_e) * (H@Wi_e), bf16.
// Tile 128x64, BK=32, 4 waves (2x2), each wave 64x32 = 4x2 MFMA tiles x2 mats.
#define BPITCH 40  // LDS row pitch in bf16 elems: 80B, 16B-aligned, conflict pad

__global__ __launch_bounds__(256) void hid_k(
    const float* __restrict__ x, const float* __restrict__ weg,
    const float* __restrict__ wei, const int* __restrict__ offsets,
    const int* __restrict__ perm, const float* __restrict__ wrow,
    unsigned short* __restrict__ hid) {
  int e = blockIdx.z;
  int off = offsets[e], end = offsets[e + 1];
  int cnt = end - off;
  int m0 = blockIdx.y * 128;
  if (m0 >= cnt) return;
  int nb = blockIdx.x * 64;
  const float* wg = weg + (size_t)e * DMODEL * DMLP;
  const float* wi = wei + (size_t)e * DMODEL * DMLP;

  __shared__ unsigned short As[128 * BPITCH];
  __shared__ unsigned short Bg[64 * BPITCH];
  __shared__ unsigned short Bi[64 * BPITCH];

  int tid = threadIdx.x;
  int lane = tid & 63, wid = tid >> 6;
  int wm = (wid & 1) * 64, wn = (wid >> 1) * 32;
  int lr = lane & 15, q = lane >> 4;

  f32x4 accg[4][2], acci[4][2];
  f32x4 z = {0.f, 0.f, 0.f, 0.f};
#pragma unroll
  for (int i = 0; i < 4; ++i)
#pragma unroll
    for (int j = 0; j < 2; ++j) { accg[i][j] = z; acci[i][j] = z; }

  // A staging plan: 1024 float4-tasks (128 rows x 8 k-groups), 4 per thread.
  const float* aptr[4];
  int adst[4];
#pragma unroll
  for (int it = 0; it < 4; ++it) {
    int task = tid + it * 256;
    int r = task >> 3, kc = (task & 7) * 4;
    int pl = m0 + r;
    int src = perm[off + ((pl < cnt) ? pl : 0)];  // clamp padding rows
    aptr[it] = x + (size_t)src * DMODEL + kc;
    adst[it] = r * BPITCH + kc;
  }
  // B staging plan: thread -> 4 cols (tn..tn+3) at rows tk,tk+1
  int tn = (tid & 15) * 4, tk = (tid >> 4) * 2;

  for (int k0 = 0; k0 < DMODEL; k0 += 32) {
    // ---- stage A (gathered fp32 -> bf16) ----
#pragma unroll
    for (int it = 0; it < 4; ++it) {
      float4 v = *(const float4*)(aptr[it] + k0);
      ushort4 u;
      u.x = f2bf(v.x); u.y = f2bf(v.y); u.z = f2bf(v.z); u.w = f2bf(v.w);
      *(ushort4*)(&As[adst[it]]) = u;
    }
    // ---- stage B gate & in (fp32 [k][n] -> bf16 LDS [n][k]) ----
    {
      const float* pg = wg + (size_t)(k0 + tk) * DMLP + nb + tn;
      float4 g0 = *(const float4*)(pg);
      float4 g1 = *(const float4*)(pg + DMLP);
      const float* pi = wi + (size_t)(k0 + tk) * DMLP + nb + tn;
      float4 i0 = *(const float4*)(pi);
      float4 i1 = *(const float4*)(pi + DMLP);
      const float* c0 = (const float*)&g0;
      const float* c1 = (const float*)&g1;
      const float* d0 = (const float*)&i0;
      const float* d1 = (const float*)&i1;
#pragma unroll
      for (int cix = 0; cix < 4; ++cix) {
        ushort2 vg; vg.x = f2bf(c0[cix]); vg.y = f2bf(c1[cix]);
        *(ushort2*)(&Bg[(tn + cix) * BPITCH + tk]) = vg;
        ushort2 vi; vi.x = f2bf(d0[cix]); vi.y = f2bf(d1[cix]);
        *(ushort2*)(&Bi[(tn + cix) * BPITCH + tk]) = vi;
      }
    }
    __syncthreads();
    // ---- compute ----
    bf16x8 af[4], bgf[2], bif[2];
#pragma unroll
    for (int i = 0; i < 4; ++i)
      af[i] = *(const bf16x8*)(&As[(wm + i * 16 + lr) * BPITCH + q * 8]);
#pragma unroll
    for (int j = 0; j < 2; ++j) {
      bgf[j] = *(const bf16x8*)(&Bg[(wn + j * 16 + lr) * BPITCH + q * 8]);
      bif[j] = *(const bf16x8*)(&Bi[(wn + j * 16 + lr) * BPITCH + q * 8]);
    }
#pragma unroll
    for (int i = 0; i < 4; ++i)
#pragma unroll
      for (int j = 0; j < 2; ++j) {
        accg[i][j] = __builtin_amdgcn_mfma_f32_16x16x32_bf16(af[i], bgf[j], accg[i][j], 0, 0, 0);
        acci[i][j] = __builtin_amdgcn_mfma_f32_16x16x32_bf16(af[i], bif[j], acci[i][j], 0, 0, 0);
      }
    __syncthreads();
  }
  // ---- epilogue: silu(g)*v * wrow -> bf16 hid ----
#pragma unroll
  for (int i = 0; i < 4; ++i)
#pragma unroll
    for (int j = 0; j < 2; ++j)
#pragma unroll
      for (int r = 0; r < 4; ++r) {
        int row = wm + i * 16 + q * 4 + r;
        int pl = m0 + row;
        if (pl < cnt) {
          int pos = off + pl;
          float g = accg[i][j][r], vv = acci[i][j][r];
          float hv = (g / (1.f + expf(-g))) * vv * wrow[pos];
          hid[(size_t)pos * DMLP + nb + wn + j * 16 + lr] = f2bf(hv);
        }
      }
}

// ---------------- kernel 4: out GEMM, atomic accumulate ----------------
__global__ __launch_bounds__(256) void out_k(
    const unsigned short* __restrict__ hid, const float* __restrict__ weo,
    const int* __restrict__ offsets, const int* __restrict__ perm,
    float* __restrict__ out) {
  int e = blockIdx.z;
  int off = offsets[e], end = offsets[e + 1];
  int cnt = end - off;
  int m0 = blockIdx.y * 128;
  if (m0 >= cnt) return;
  int nb = blockIdx.x * 64;
  const float* wo = weo + (size_t)e * DMLP * DMODEL;

  __shared__ unsigned short As[128 * BPITCH];
  __shared__ unsigned short Bs[64 * BPITCH];

  int tid = threadIdx.x;
  int lane = tid & 63, wid = tid >> 6;
  int wm = (wid & 1) * 64, wn = (wid >> 1) * 32;
  int lr = lane & 15, q = lane >> 4;

  f32x4 acc[4][2];
  f32x4 z = {0.f, 0.f, 0.f, 0.f};
#pragma unroll
  for (int i = 0; i < 4; ++i)
#pragma unroll
    for (int j = 0; j < 2; ++j) acc[i][j] = z;

  // A staging plan: 512 tasks (128 rows x 4 groups of 8 bf16), 2 per thread
  const unsigned short* aptr[2];
  int adst[2];
#pragma unroll
  for (int it = 0; it < 2; ++it) {
    int task = tid + it * 256;
    int r = task >> 2, kg = (task & 3) * 8;
    int pl = m0 + r;
    int src = off + ((pl < cnt) ? pl : 0);
    aptr[it] = hid + (size_t)src * DMLP + kg;
    adst[it] = r * BPITCH + kg;
  }
  int tn = (tid & 15) * 4, tk = (tid >> 4) * 2;

  for (int k0 = 0; k0 < DMLP; k0 += 32) {
    // ---- stage A (bf16 passthrough, 16B) ----
#pragma unroll
    for (int it = 0; it < 2; ++it) {
      uint4 v = *(const uint4*)(aptr[it] + k0);
      *(uint4*)(&As[adst[it]]) = v;
    }
    // ---- stage B (Wo fp32 [k][n] -> bf16 LDS [n][k]) ----
    {
      const float* pb = wo + (size_t)(k0 + tk) * DMODEL + nb + tn;
      float4 b0 = *(const float4*)(pb);
      float4 b1 = *(const float4*)(pb + DMODEL);
      const float* c0 = (const float*)&b0;
      const float* c1 = (const float*)&b1;
#pragma unroll
      for (int cix = 0; cix < 4; ++cix) {
        ushort2 vb; vb.x = f2bf(c0[cix]); vb.y = f2bf(c1[cix]);
        *(ushort2*)(&Bs[(tn + cix) * BPITCH + tk]) = vb;
      }
    }
    __syncthreads();
    // ---- compute ----
    bf16x8 af[4], bf[2];
#pragma unroll
    for (int i = 0; i < 4; ++i)
      af[i] = *(const bf16x8*)(&As[(wm + i * 16 + lr) * BPITCH + q * 8]);
#pragma unroll
    for (int j = 0; j < 2; ++j)
      bf[j] = *(const bf16x8*)(&Bs[(wn + j * 16 + lr) * BPITCH + q * 8]);
#pragma unroll
    for (int i = 0; i < 4; ++i)
#pragma unroll
      for (int j = 0; j < 2; ++j)
        acc[i][j] = __builtin_amdgcn_mfma_f32_16x16x32_bf16(af[i], bf[j], acc[i][j], 0, 0, 0);
    __syncthreads();
  }
  // ---- epilogue: scatter-add into out (2 commutative fp32 adds/elem) ----
#pragma unroll
  for (int i = 0; i < 4; ++i)
#pragma unroll
    for (int j = 0; j < 2; ++j)
#pragma unroll
      for (int r = 0; r < 4; ++r) {
        int row = wm + i * 16 + q * 4 + r;
        int pl = m0 + row;
        if (pl < cnt) {
          int tok = perm[off + pl];
          atomicAdd(&out[(size_t)tok * DMODEL + nb + wn + j * 16 + lr],
                    acc[i][j][r]);
        }
      }
}

// ---------------- launcher ----------------
extern "C" void kernel_launch(void* const* d_in, const int* in_sizes, int n_in,
                              void* d_out, int out_size, void* d_ws,
                              size_t ws_size, hipStream_t stream) {
  const float* x = (const float*)d_in[0];
  const float* wgate = (const float*)d_in[1];
  const float* weg = (const float*)d_in[2];
  const float* wei = (const float*)d_in[3];
  const float* weo = (const float*)d_in[4];
  float* out = (float*)d_out;

  char* ws = (char*)d_ws;
  // ws layout (all offsets 16B-aligned):
  int* topi = (int*)(ws + 0);                 // 4096 ints
  float* topw = (float*)(ws + (16 << 10));    // 4096 f32
  int* offsets = (int*)(ws + (32 << 10));     // 9 ints
  int* perm = (int*)(ws + (33 << 10));        // 4096 ints
  float* wrow = (float*)(ws + (49 << 10));    // 4096 f32
  unsigned short* hid = (unsigned short*)(ws + (65 << 10));  // 4096x4096 bf16 (32MB)

  hipMemsetAsync(d_out, 0, (size_t)out_size * sizeof(float), stream);
  router_k<<<dim3(T_TOK), dim3(64), 0, stream>>>(x, wgate, topi, topw);
  compact_k<<<dim3(1), dim3(512), 0, stream>>>(topi, topw, offsets, perm, wrow);
  hid_k<<<dim3(DMLP / 64, T_TOK / 128, NEXP), dim3(256), 0, stream>>>(
      x, weg, wei, offsets, perm, wrow, hid);
  out_k<<<dim3(DMODEL / 64, T_TOK / 128, NEXP), dim3(256), 0, stream>>>(
      hid, weo, offsets, perm, out);
}